// Round 7
// baseline (1467.144 us; speedup 1.0000x reference)
//
#include <hip/hip_runtime.h>
#include <cstdint>
#include <cstddef>
#include <type_traits>

#define T_STEPS 16
#define BB 512
#define NF 1024
#define NI 256
#define NH 2048
#define KSTEPS 5

typedef __bf16 bf16;
typedef __bf16 bf16x8 __attribute__((ext_vector_type(8)));
typedef __bf16 bf16x4 __attribute__((ext_vector_type(4)));
typedef float f32x4 __attribute__((ext_vector_type(4)));

enum { EPI_BF16 = 0, EPI_F32 = 1, EPI_TEMPS = 2, EPI_W1 = 3 };

__device__ __forceinline__ void gload_lds16(const bf16* g, void* l) {
  __builtin_amdgcn_global_load_lds(
      (const __attribute__((address_space(1))) void*)g,
      (__attribute__((address_space(3))) void*)l, 16, 0, 0);
}
// sc0 (glc): bypass per-CU L1, serve from the XCD's L2 (intra-XCD coherent)
__device__ __forceinline__ void gload_lds16_glc(const bf16* g, void* l) {
  __builtin_amdgcn_global_load_lds(
      (const __attribute__((address_space(1))) void*)g,
      (__attribute__((address_space(3))) void*)l, 16, 0, 1);
}

// faithful multi-branch prox of w0*|x| + w1*|x - a1|
__device__ __forceinline__ float soft_l1_l1(float z, float w0, float w1, float a1) {
  bool c = (0.0f <= a1);
  float a0s = c ? 0.0f : a1;
  float a1s = c ? a1 : 0.0f;
  float w0s = c ? w0 : w1;
  float w1s = c ? w1 : w0;
  if (z >= a1s + w0s + w1s) return z - w0s - w1s;
  if (z >= a1s + w0s - w1s) return a1s;
  if (z >= a0s + w0s - w1s) return z - w0s + w1s;
  if (z >= a0s - w0s - w1s) return a0s;
  return z + w0s + w1s;
}

// ---------------------------------------------------------------------------
// Batched GEMM (unchanged): 128x128 tile, BK=64, D=2, counted vmcnt(8) + raw
// barriers, XCD chunking with col-fastest decode.
// ---------------------------------------------------------------------------
template<int EPI>
__global__ __launch_bounds__(256)
void gemm_bt2(const bf16* __restrict__ Ag, const bf16* __restrict__ Bg,
              int N, int Kd, int nby, int total,
              bf16* __restrict__ outb, float* __restrict__ outf,
              bf16* __restrict__ out2, const float* __restrict__ srcf,
              const float* __restrict__ alpha, int inv_alpha)
{
  __shared__ char smem[65536];
  const int tid = threadIdx.x, lane = tid & 63, wid = tid >> 6;
  const int wr = wid >> 1, wc = wid & 1;
  const int r16 = lane & 15, q16 = lane >> 4;
  const int bid = blockIdx.x;
  const int wg = (bid & 7) * (total >> 3) + (bid >> 3);
  const int bm0 = (wg / nby) * 128, bn0 = (wg % nby) * 128;
  const int sw = r16 & 7;

  f32x4 acc[4][4] = {};

  auto stage = [&](int buf, int kt) {
    char* da = smem + buf * 32768;
    char* db = da + 16384;
#pragma unroll
    for (int it = 0; it < 4; ++it) {
      int idx = it * 256 + tid;
      int row = idx >> 3, sc = (idx & 7) ^ (row & 7);
      gload_lds16(Ag + (size_t)(bm0 + row) * Kd + kt + sc * 8, da + idx * 16);
    }
#pragma unroll
    for (int it = 0; it < 4; ++it) {
      int idx = it * 256 + tid;
      int row = idx >> 3, sc = (idx & 7) ^ (row & 7);
      gload_lds16(Bg + (size_t)(bn0 + row) * Kd + kt + sc * 8, db + idx * 16);
    }
  };

  auto compute = [&](int buf) {
    const char* Ab = smem + buf * 32768;
    const char* Bb = Ab + 16384;
#pragma unroll
    for (int kk = 0; kk < 2; ++kk) {
      int ch = ((kk * 4 + q16) ^ sw) * 16;
      bf16x8 af[4], bfr[4];
#pragma unroll
      for (int i = 0; i < 4; ++i)
        af[i] = *(const bf16x8*)(Ab + (wr * 64 + i * 16 + r16) * 128 + ch);
#pragma unroll
      for (int j = 0; j < 4; ++j)
        bfr[j] = *(const bf16x8*)(Bb + (wc * 64 + j * 16 + r16) * 128 + ch);
#pragma unroll
      for (int i = 0; i < 4; ++i)
#pragma unroll
        for (int j = 0; j < 4; ++j)
          acc[i][j] = __builtin_amdgcn_mfma_f32_16x16x32_bf16(af[i], bfr[j], acc[i][j], 0, 0, 0);
    }
  };

  const int NT = Kd >> 6;
  stage(0, 0);
  int t = 0;
  for (; t < NT - 1; ++t) {
    stage((t + 1) & 1, (t + 1) * 64);
    asm volatile("s_waitcnt vmcnt(8)" ::: "memory");
    __builtin_amdgcn_s_barrier();
    __builtin_amdgcn_sched_barrier(0);
    compute(t & 1);
    __builtin_amdgcn_sched_barrier(0);
    __builtin_amdgcn_s_barrier();
  }
  asm volatile("s_waitcnt vmcnt(0)" ::: "memory");
  __builtin_amdgcn_s_barrier();
  __builtin_amdgcn_sched_barrier(0);
  compute(t & 1);

  float scale = inv_alpha ? 1.f / alpha[0] : 1.f;
#pragma unroll
  for (int i = 0; i < 4; ++i) {
#pragma unroll
    for (int j = 0; j < 4; ++j) {
#pragma unroll
      for (int e = 0; e < 4; ++e) {
        int m = bm0 + wr * 64 + i * 16 + q16 * 4 + e;
        int n = bn0 + wc * 64 + j * 16 + r16;
        size_t o = (size_t)m * N + n;
        float v = acc[i][j][e] * scale;
        if (EPI == EPI_BF16) {
          outb[o] = (bf16)v;
        } else if (EPI == EPI_F32) {
          outf[o] = v;
        } else if (EPI == EPI_TEMPS) {
          outb[o] = (bf16)v;
          out2[o] = (bf16)((m == n ? 1.f : 0.f) - v);
        } else { // EPI_W1
          outb[o] = (bf16)(srcf[o] - v);
        }
      }
    }
  }
}

// ---------------------------------------------------------------------------
// Persistent scan v3 — XCD-LOCAL recurrence. The prox recurrence never mixes
// batch rows, so XCD x owns h rows [x*64, x*64+64) for the WHOLE scan:
// its 32 blocks (2 row-tiles x 16 col-tiles of 32x128) write AND read h only
// within x's L2 (intra-XCD coherence point). No fences, no MALL round trips;
// h loads use sc0 (L1 bypass) to dodge per-CU L1 staleness (G16). Weights S
// (full 8 MB) stream through each XCD's L2 from L3 every phase — D=3 LDS
// pipeline gives a 2-tile latency budget over L3. Barrier = per-XCD only
// (32 blocks, relaxed atomics, no master). LDS swizzle: full-row XOR
// sc=(idx&15)^(row&15), read ch=(kk*4+q16)^r16.
// ---------------------------------------------------------------------------
__device__ __forceinline__ void stage_w_next(char* smem, const bf16* B1,
                                             const bf16* B2, bool dual,
                                             int bn0, int tid) {
  char* base = smem + 8192;   // buf0 B1 area (common to both layouts)
#pragma unroll
  for (int it = 0; it < 8; ++it) {
    int idx = it * 256 + tid;
    int row = idx >> 4, sc = (idx & 15) ^ (row & 15);
    gload_lds16(B1 + (size_t)(bn0 + row) * NH + sc * 8, base + idx * 16);
  }
  if (dual) {
    char* g = smem + 40960;   // buf0 B2 area (DUAL layout)
#pragma unroll
    for (int it = 0; it < 8; ++it) {
      int idx = it * 256 + tid;
      int row = idx >> 4, sc = (idx & 15) ^ (row & 15);
      gload_lds16(B2 + (size_t)(bn0 + row) * NH + sc * 8, g + idx * 16);
    }
  }
}

template<bool DUAL>
__device__ __forceinline__ void phase_gemm(char* smem, const bf16* hp,
    const bf16* B1, const bf16* B2, int bm0, int bn0, int tid,
    f32x4 (&acc)[2][2], f32x4 (&accG)[2][2])
{
  const int lane = tid & 63, wid = tid >> 6;
  const int r16 = lane & 15, q16 = lane >> 4;
  constexpr int BSTR = DUAL ? 73728 : 40960;  // A 8K @0, B1 32K @8192 (+B2 @40960)
  constexpr int D = DUAL ? 2 : 3;

#pragma unroll
  for (int i = 0; i < 2; ++i)
#pragma unroll
    for (int j = 0; j < 2; ++j) {
      acc[i][j] = f32x4{0.f, 0.f, 0.f, 0.f};
      if constexpr (DUAL) accG[i][j] = f32x4{0.f, 0.f, 0.f, 0.f};
    }

  auto stageA = [&](int buf, int kt) {
    char* base = smem + buf * BSTR;
#pragma unroll
    for (int it = 0; it < 2; ++it) {
      int idx = it * 256 + tid;
      int row = idx >> 4, sc = (idx & 15) ^ (row & 15);
      gload_lds16_glc(hp + (size_t)(bm0 + row) * NH + kt + sc * 8, base + idx * 16);
    }
  };
  auto stageB = [&](int buf, int kt) {
    char* base = smem + buf * BSTR + 8192;
#pragma unroll
    for (int it = 0; it < 8; ++it) {
      int idx = it * 256 + tid;
      int row = idx >> 4, sc = (idx & 15) ^ (row & 15);
      gload_lds16(B1 + (size_t)(bn0 + row) * NH + kt + sc * 8, base + idx * 16);
    }
    if constexpr (DUAL) {
      char* g = smem + buf * BSTR + 40960;
#pragma unroll
      for (int it = 0; it < 8; ++it) {
        int idx = it * 256 + tid;
        int row = idx >> 4, sc = (idx & 15) ^ (row & 15);
        gload_lds16(B2 + (size_t)(bn0 + row) * NH + kt + sc * 8, g + idx * 16);
      }
    }
  };
  auto compute = [&](int buf) {
    const char* Ab = smem + buf * BSTR;
    const char* Bb = Ab + 8192;
    const char* Gb = Ab + 40960;
#pragma unroll
    for (int kk = 0; kk < 4; ++kk) {
      const int ch = ((kk * 4 + q16) ^ r16) * 16;
      bf16x8 af[2], bf_[2];
#pragma unroll
      for (int i = 0; i < 2; ++i)
        af[i] = *(const bf16x8*)(Ab + (i * 16 + r16) * 256 + ch);
#pragma unroll
      for (int j = 0; j < 2; ++j)
        bf_[j] = *(const bf16x8*)(Bb + (wid * 32 + j * 16 + r16) * 256 + ch);
#pragma unroll
      for (int i = 0; i < 2; ++i)
#pragma unroll
        for (int j = 0; j < 2; ++j)
          acc[i][j] = __builtin_amdgcn_mfma_f32_16x16x32_bf16(af[i], bf_[j], acc[i][j], 0, 0, 0);
      if constexpr (DUAL) {
        bf16x8 bg[2];
#pragma unroll
        for (int j = 0; j < 2; ++j)
          bg[j] = *(const bf16x8*)(Gb + (wid * 32 + j * 16 + r16) * 256 + ch);
#pragma unroll
        for (int i = 0; i < 2; ++i)
#pragma unroll
          for (int j = 0; j < 2; ++j)
            accG[i][j] = __builtin_amdgcn_mfma_f32_16x16x32_bf16(af[i], bg[j], accG[i][j], 0, 0, 0);
      }
    }
  };

  // prologue: buf0-B was prefetched under the previous barrier
  stageA(0, 0);
  stageA(1, 128); stageB(1, 128);
  if constexpr (!DUAL) { stageA(2, 256); stageB(2, 256); }

#pragma unroll 1
  for (int tt = 0; tt < 16; ++tt) {
    if constexpr (DUAL) {
      if (tt < 15) asm volatile("s_waitcnt vmcnt(18)" ::: "memory");
      else         asm volatile("s_waitcnt vmcnt(0)" ::: "memory");
    } else {
      if (tt < 14)       asm volatile("s_waitcnt vmcnt(20)" ::: "memory");
      else if (tt == 14) asm volatile("s_waitcnt vmcnt(10)" ::: "memory");
      else               asm volatile("s_waitcnt vmcnt(0)" ::: "memory");
    }
    __builtin_amdgcn_s_barrier();
    __builtin_amdgcn_sched_barrier(0);
    compute(tt % D);
    __builtin_amdgcn_sched_barrier(0);
    __builtin_amdgcn_s_barrier();
    if (tt + D <= 15) {        // stage into the just-freed buffer
      stageA(tt % D, (tt + D) * 128);
      stageB(tt % D, (tt + D) * 128);
    }
  }
}

__global__ __launch_bounds__(256, 1)
void scan_persist(const bf16* __restrict__ H0, const bf16* __restrict__ W1m,
                  const bf16* __restrict__ Sm, const bf16* __restrict__ Gt,
                  const bf16* __restrict__ XV, bf16* __restrict__ Hb0,
                  bf16* __restrict__ Hb1, bf16* __restrict__ HS,
                  const float* __restrict__ alpha, const float* __restrict__ lam0,
                  const float* __restrict__ lam1, unsigned* __restrict__ cnt)
{
  __shared__ char smem[147456];
  const int tid = threadIdx.x, lane = tid & 63, wid = tid >> 6;
  const int r16 = lane & 15, q16 = lane >> 4;
  const int bid = blockIdx.x;
  const int xcd = bid & 7, r = bid >> 3;
  const int ct = r & 15, rt = r >> 4;        // 16 col-tiles x 2 row-tiles
  const int bm0 = xcd * 64 + rt * 32;        // XCD x owns h rows [x*64, x*64+64)
  const int bn0 = ct * 128;

  const float al = alpha[0];
  const float w0 = lam0[0] / al, w1 = lam1[0] / al;
  const size_t HBsz = (size_t)BB * NH;

  unsigned* mycnt = cnt + xcd * 32;          // per-XCD counter, 128B apart

  unsigned bar_no = 0;
  f32x4 acc[2][2], accG[2][2];
  float xvreg[16], a1reg[16];

  stage_w_next(smem, W1m, Gt, true, bn0, tid);   // prefetch phase-0 weights

#pragma unroll 1
  for (int p = 0; p < T_STEPS * KSTEPS; ++p) {
    const int t = p / KSTEPS, k = p % KSTEPS;
    const bf16* hp;
    bf16* dst;
    if (k == 0) {
      hp = (t == 0) ? H0 : HS + (size_t)(t - 1) * HBsz;
      dst = Hb0;
    } else {
      hp = (k & 1) ? Hb0 : Hb1;
      dst = (k == KSTEPS - 1) ? HS + (size_t)t * HBsz : ((k & 1) ? Hb1 : Hb0);
    }

    if (k == 0) {
      const bf16* xvt = XV + (size_t)t * HBsz;
#pragma unroll
      for (int i = 0; i < 2; ++i)
#pragma unroll
        for (int j = 0; j < 2; ++j)
#pragma unroll
          for (int e = 0; e < 4; ++e)
            xvreg[(i * 2 + j) * 4 + e] =
                (float)xvt[(size_t)(bm0 + i * 16 + q16 * 4 + e) * NH
                           + bn0 + wid * 32 + j * 16 + r16];
      phase_gemm<true>(smem, hp, W1m, Gt, bm0, bn0, tid, acc, accG);
#pragma unroll
      for (int i = 0; i < 2; ++i)
#pragma unroll
        for (int j = 0; j < 2; ++j)
#pragma unroll
          for (int e = 0; e < 4; ++e)
            a1reg[(i * 2 + j) * 4 + e] = accG[i][j][e];
    } else {
      phase_gemm<false>(smem, hp, Sm, nullptr, bm0, bn0, tid, acc, accG);
    }

    // epilogue: shrink + plain stores (stay within this XCD's L2)
#pragma unroll
    for (int i = 0; i < 2; ++i)
#pragma unroll
      for (int j = 0; j < 2; ++j)
#pragma unroll
        for (int e = 0; e < 4; ++e) {
          float z = acc[i][j][e] + xvreg[(i * 2 + j) * 4 + e];
          float h = soft_l1_l1(z, w0, w1, a1reg[(i * 2 + j) * 4 + e]);
          dst[(size_t)(bm0 + i * 16 + q16 * 4 + e) * NH
              + bn0 + wid * 32 + j * 16 + r16] = (bf16)h;
        }

    asm volatile("s_waitcnt vmcnt(0)" ::: "memory");   // h stores at L2
    __builtin_amdgcn_s_barrier();                      // all waves drained
    if (p + 1 < T_STEPS * KSTEPS) {                    // prefetch under barrier
      bool ndual = ((p + 1) % KSTEPS) == 0;
      stage_w_next(smem, ndual ? W1m : Sm, Gt, ndual, bn0, tid);
    }
    ++bar_no;
    if (tid == 0) {   // per-XCD barrier: 32 blocks, relaxed, no fences
      __hip_atomic_fetch_add(mycnt, 1u, __ATOMIC_RELAXED, __HIP_MEMORY_SCOPE_AGENT);
      while (__hip_atomic_load(mycnt, __ATOMIC_RELAXED, __HIP_MEMORY_SCOPE_AGENT)
             < 32u * bar_no)
        __builtin_amdgcn_s_sleep(1);
    }
    __builtin_amdgcn_s_barrier();
    __builtin_amdgcn_sched_barrier(0);
  }
}

__global__ void zero_u32s(unsigned* p, int n) {
  int i = blockIdx.x * 256 + threadIdx.x;
  if (i < n) p[i] = 0;
}

__global__ void cast_f32_bf16(const float* __restrict__ in, bf16* __restrict__ out, int n) {
  int i = (blockIdx.x * blockDim.x + threadIdx.x) * 4;
  if (i + 4 <= n) {
    float4 v = *(const float4*)&in[i];
    bf16x4 p;
    p[0] = (bf16)v.x; p[1] = (bf16)v.y; p[2] = (bf16)v.z; p[3] = (bf16)v.w;
    *(bf16x4*)&out[i] = p;
  } else {
    for (; i < n; ++i) out[i] = (bf16)in[i];
  }
}

// out[c,r] = (bf16) in[r,c];  in: [R,C] f32 row-major -> out: [C,R] bf16 row-major
__global__ void transpose_cast(const float* __restrict__ in, bf16* __restrict__ out, int R, int C) {
  __shared__ float tile[32][33];
  int bx = blockIdx.x * 32, by = blockIdx.y * 32;
  int tx = threadIdx.x, ty = threadIdx.y;
  for (int i = ty; i < 32; i += 8) {
    int r = by + i, c = bx + tx;
    if (r < R && c < C) tile[i][tx] = in[(size_t)r * C + c];
  }
  __syncthreads();
  for (int i = ty; i < 32; i += 8) {
    int r = bx + i, c = by + tx;
    if (r < C && c < R) out[(size_t)r * R + c] = (bf16)tile[tx][i];
  }
}

extern "C" void kernel_launch(void* const* d_in, const int* in_sizes, int n_in,
                              void* d_out, int out_size, void* d_ws, size_t ws_size,
                              hipStream_t stream) {
  // inputs: 0 pre_input (unused), 1 raw, 2 A, 3 D, 4 G, 5 h_0,
  //         6 alpha, 7 lambda0, 8 lambda1, 9 K (fixed = 5)
  const float* rawf = (const float*)d_in[1];
  const float* Af   = (const float*)d_in[2];
  const float* Df   = (const float*)d_in[3];
  const float* Gf   = (const float*)d_in[4];
  const float* h0f  = (const float*)d_in[5];
  const float* alp  = (const float*)d_in[6];
  const float* l0   = (const float*)d_in[7];
  const float* l1   = (const float*)d_in[8];
  float* outp = (float*)d_out;

  char* w = (char*)d_ws;
  auto allocb = [&](size_t bytes) { char* p = w; w += (bytes + 255) & ~(size_t)255; return p; };
  bf16* Abf  = (bf16*)allocb((size_t)NI * NF * 2);
  bf16* At   = (bf16*)allocb((size_t)NF * NI * 2);
  bf16* Dbf  = (bf16*)allocb((size_t)NF * NH * 2);
  bf16* Dt   = (bf16*)allocb((size_t)NH * NF * 2);
  bf16* Gt   = (bf16*)allocb((size_t)NH * NH * 2);
  bf16* rawb = (bf16*)allocb((size_t)T_STEPS * BB * NF * 2);
  bf16* AtA  = (bf16*)allocb((size_t)NF * NF * 2);
  bf16* Vm   = (bf16*)allocb((size_t)NH * NI * 2);
  bf16* M3t  = (bf16*)allocb((size_t)NH * NF * 2);
  bf16* tmpb = (bf16*)allocb((size_t)NH * NH * 2);
  bf16* Sm   = (bf16*)allocb((size_t)NH * NH * 2);
  bf16* W1m  = (bf16*)allocb((size_t)NH * NH * 2);
  bf16* X    = (bf16*)allocb((size_t)T_STEPS * BB * NI * 2);
  bf16* H0   = (bf16*)allocb((size_t)BB * NH * 2);
  bf16* Hb0  = (bf16*)allocb((size_t)BB * NH * 2);
  bf16* Hb1  = (bf16*)allocb((size_t)BB * NH * 2);
  bf16* HS   = (bf16*)allocb((size_t)T_STEPS * BB * NH * 2);
  unsigned* cnt = (unsigned*)allocb(4096);
  // XV (T*B x NH bf16 = 33.5 MB) lives in d_out: fully written before use, dead
  // before the final projection overwrites d_out.
  bf16* XV   = (bf16*)d_out;

  zero_u32s<<<dim3(2), 256, 0, stream>>>(cnt, 512);

  auto cgrid = [](int n) { return dim3((unsigned)((n / 4 + 255) / 256)); };
  cast_f32_bf16<<<cgrid(NI * NF), 256, 0, stream>>>(Af, Abf, NI * NF);
  cast_f32_bf16<<<cgrid(NF * NH), 256, 0, stream>>>(Df, Dbf, NF * NH);
  cast_f32_bf16<<<cgrid(T_STEPS * BB * NF), 256, 0, stream>>>(rawf, rawb, T_STEPS * BB * NF);
  cast_f32_bf16<<<cgrid(BB * NH), 256, 0, stream>>>(h0f, H0, BB * NH);
  transpose_cast<<<dim3(NF / 32, NI / 32), dim3(32, 8), 0, stream>>>(Af, At, NI, NF);
  transpose_cast<<<dim3(NH / 32, NF / 32), dim3(32, 8), 0, stream>>>(Df, Dt, NF, NH);
  transpose_cast<<<dim3(NH / 32, NH / 32), dim3(32, 8), 0, stream>>>(Gf, Gt, NH, NH);

  auto launch_bt2 = [&](auto epi_tag, int Mrows, int Ncols, int Kd,
                        const bf16* Ap, const bf16* Bp,
                        bf16* ob, float* of, bf16* o2, const float* sf, int inva) {
    constexpr int EPIv = decltype(epi_tag)::value;
    int nbx = Mrows / 128, nby = Ncols / 128, total = nbx * nby;
    gemm_bt2<EPIv><<<dim3(total), 256, 0, stream>>>(
        Ap, Bp, Ncols, Kd, nby, total, ob, of, o2, sf, alp, inva);
  };

  // AtA[f1,f2] = sum_i A[i,f1]A[i,f2]
  launch_bt2(std::integral_constant<int, EPI_BF16>{}, NF, NF, NI, At, At,
             AtA, nullptr, nullptr, nullptr, 0);
  // V[h,i] = (1/al) sum_f D[f,h]A[i,f]
  launch_bt2(std::integral_constant<int, EPI_BF16>{}, NH, NI, NF, Dt, Abf,
             Vm, nullptr, nullptr, nullptr, 1);
  // M3t[h,f] = sum_f2 Dt[h,f2]AtA[f,f2] = (AtA@D)[f,h]  (AtA symmetric)
  launch_bt2(std::integral_constant<int, EPI_BF16>{}, NH, NF, NF, Dt, AtA,
             M3t, nullptr, nullptr, nullptr, 0);
  // temp = (1/al) D^T (AtA D); S = I - temp (dual store)
  launch_bt2(std::integral_constant<int, EPI_TEMPS>{}, NH, NH, NF, Dt, M3t,
             tmpb, nullptr, Sm, nullptr, 1);
  // W1 = G - temp@G
  launch_bt2(std::integral_constant<int, EPI_W1>{}, NH, NH, NH, tmpb, Gt,
             W1m, nullptr, nullptr, Gf, 0);
  // X = raw @ A^T
  launch_bt2(std::integral_constant<int, EPI_BF16>{}, T_STEPS * BB, NI, NF, rawb, Abf,
             X, nullptr, nullptr, nullptr, 0);
  // XV = X @ V^T
  launch_bt2(std::integral_constant<int, EPI_BF16>{}, T_STEPS * BB, NH, NI, X, Vm,
             XV, nullptr, nullptr, nullptr, 0);

  // Entire scan (16 t-steps x 5 prox iterations) in ONE persistent kernel,
  // 8 independent per-XCD recurrences.
  scan_persist<<<dim3(256), 256, 0, stream>>>(
      H0, W1m, Sm, Gt, XV, Hb0, Hb1, HS, alp, l0, l1, cnt);

  // z_hat = HS @ D^T (fp32 direct to d_out)
  launch_bt2(std::integral_constant<int, EPI_F32>{}, T_STEPS * BB, NF, NH, HS, Dbf,
             nullptr, outp, nullptr, nullptr, 0);
}